// Round 21
// baseline (577.598 us; speedup 1.0000x reference)
//
#include <hip/hip_runtime.h>

// Steerable pyramid via MFMA, fp32 I/O, bf16 compute.
// *** r21 = DIAGNOSTIC ROUND ***: dual_mfma32 and scale_comb<8> repeat
// their (idempotent) work REP=8 times with a memory-clobber between reps,
// making them slower than the harness poison-fills so rocprof top-5 shows
// their true counters (Occupancy/VALUBusy/MfmaUtil/FETCH/WRITE).
// Outputs are rewritten with identical values -> correctness unchanged.
// Everything else is byte-identical to r20 (best: 116.8 us).

typedef __attribute__((ext_vector_type(8))) short short8v;
typedef __attribute__((ext_vector_type(4))) float f32x4;
typedef __attribute__((ext_vector_type(16))) float f32x16;

static __device__ __forceinline__ unsigned short f2bf(float f) {
    union { float f; unsigned u; } v; v.f = f;
    unsigned u = v.u;
    u += 0x7fffu + ((u >> 16) & 1u);
    return (unsigned short)(u >> 16);
}

static __device__ __forceinline__ unsigned pack2(float a, float b) {
    return (unsigned)f2bf(a) | ((unsigned)f2bf(b) << 16);
}

static __device__ __forceinline__ void nt_storef(float* p, float v) {
    __builtin_nontemporal_store(v, p);
}

// AF fragment table rows (entry = short8v per lane, row*64+l):
// [0..8] bands32 dy | [9..18] dual32 i | [19..35] down A1 | [36..52] down A2

// ---------------------------------------------------------------- prep

static __device__ __forceinline__ void do_build_frags(
    const float* bf, const float* fh, const float* fl, const float* lfilt,
    unsigned short* AF, int id)
{
    if (id >= 53 * 64) return;
    int row = id >> 6, l = id & 63;
    short8v a;
    if (row < 9) {
        int dy = row;
        int m = l & 31, f = m >> 3, p = m & 7, kb = (l >> 5) * 8;
        #pragma unroll
        for (int i = 0; i < 8; ++i) {
            int d = kb + i - p;
            a[i] = (short)((d >= 0 && d < 9) ? f2bf(bf[f * 81 + dy * 9 + d]) : 0);
        }
    } else if (row < 19) {
        int is = row - 9;
        int m = l & 31, ry = m >> 4, f = (m >> 3) & 1, p = m & 7, kb = (l >> 5) * 8;
        int dy = is - ry;
        const float* fr = f ? fl : fh;
        #pragma unroll
        for (int i = 0; i < 8; ++i) {
            int dx = kb + i - p;
            bool ok = (dy >= 0 && dy < 9) && (dx >= 0 && dx < 9);
            a[i] = (short)(ok ? f2bf(fr[dy * 9 + dx]) : 0);
        }
    } else if (row < 36) {
        int dy = row - 19;
        int m = l & 15, kb = (l >> 4) * 8;
        #pragma unroll
        for (int i = 0; i < 8; ++i) {
            int d = kb + i - 2 * m;
            a[i] = (short)((d >= 0 && d < 17) ? f2bf(lfilt[dy * 17 + d]) : 0);
        }
    } else {
        int dy = row - 36;
        int m = l & 15, kb = (l >> 4) * 8;
        #pragma unroll
        for (int i = 0; i < 8; ++i) {
            int d = 32 + kb + i - 2 * m;
            a[i] = (short)((d >= 0 && d < 17) ? f2bf(lfilt[dy * 17 + d]) : 0);
        }
    }
    *(short8v*)(AF + (size_t)id * 8) = a;
}

static __device__ __forceinline__ void zero_cx_vec(
    unsigned short* buf, int W, int id)
{
    int Wp = W + 16, Wv = Wp >> 3;
    int rowT = 16 * 16 * Wv;
    int perN = rowT + W * 32;
    int n = id / perN;
    int r = id - n * perN;
    int y, c, xv;
    if (r < rowT) {
        int ry = r / (16 * Wv);
        int rem = r - ry * (16 * Wv);
        c = rem / Wv;
        xv = rem - c * Wv;
        y = (ry < 8) ? ry : ry + W;
    } else {
        int r2 = r - rowT;
        y = 8 + (r2 >> 5);
        int rem = r2 & 31;
        c = rem >> 1;
        xv = (rem & 1) ? (Wv - 1) : 0;
    }
    short8v z = {0, 0, 0, 0, 0, 0, 0, 0};
    *(short8v*)(buf + ((size_t)(n * Wp + y) * 16 + c) * Wp + xv * 8) = z;
}

// prep_all: [0,14) build_frags | [14,1038) zero_pads | [1038,3150) img_to_cx.
__global__ __launch_bounds__(256) void prep_all(
    const float* __restrict__ bf, const float* __restrict__ fh,
    const float* __restrict__ fl, const float* __restrict__ lfilt,
    unsigned short* __restrict__ AF,
    unsigned short* __restrict__ L0, unsigned short* __restrict__ L1,
    unsigned short* __restrict__ L2, unsigned short* __restrict__ L3,
    const float4* __restrict__ src4, unsigned short* __restrict__ IMG)
{
    __shared__ unsigned short lds[16][264];
    int b = blockIdx.x, t = threadIdx.x;
    if (b < 14) {
        do_build_frags(bf, fh, fl, lfilt, AF, b * 256 + t);
    } else if (b < 1038) {
        int zb = b - 14;
        if (zb < 528)      zero_cx_vec(L0, 256, zb * 256 + t);
        else if (zb < 800) zero_cx_vec(L1, 128, (zb - 528) * 256 + t);
        else if (zb < 944) zero_cx_vec(L2, 64,  (zb - 800) * 256 + t);
        else               zero_cx_vec(L3, 32,  (zb - 944) * 256 + t);
    } else {
        int ib = b - 1038;                   // 2112 = 8 * 264
        int n = ib & 7;
        int yp = ib >> 3;
        int y = yp - 4;
        unsigned short* drow = IMG + ((size_t)(n * 264 + yp) * 16) * 264;
        if ((unsigned)y < 256u) {
            for (int task = t; task < 1056; task += 256) {
                int px = task >> 2, cg = task & 3;
                int xs = px - 4;
                bool ok = (unsigned)xs < 256u;
                int xc = min(max(xs, 0), 255);
                float4 v = src4[((size_t)(n * 256 + y) * 256 + xc) * 4 + cg];
                lds[cg * 4 + 0][px] = (unsigned short)(ok ? f2bf(v.x) : 0);
                lds[cg * 4 + 1][px] = (unsigned short)(ok ? f2bf(v.y) : 0);
                lds[cg * 4 + 2][px] = (unsigned short)(ok ? f2bf(v.z) : 0);
                lds[cg * 4 + 3][px] = (unsigned short)(ok ? f2bf(v.w) : 0);
            }
            __syncthreads();
            for (int task = t; task < 528; task += 256) {
                int c = task / 33, xg = task - c * 33;
                short8v v = *(const short8v*)&lds[c][xg * 8];
                *(short8v*)(drow + (size_t)c * 264 + xg * 8) = v;
            }
        } else {
            short8v z = {0, 0, 0, 0, 0, 0, 0, 0};
            for (int task = t; task < 528; task += 256) {
                int c = task / 33, xg = task - c * 33;
                *(short8v*)(drow + (size_t)c * 264 + xg * 8) = z;
            }
        }
    }
}

// ---------------------------------------------------------------- MFMA convs

#define MFMA16 __builtin_amdgcn_mfma_f32_16x16x32_bf16
#define MFMA32 __builtin_amdgcn_mfma_f32_32x32x16_bf16

// hi0 + lo0 from IMG CX (pad 4), 32x32x16, M = 2 rows x 2 filt x 8 px.
// DIAGNOSTIC: REP=8 idempotent repeats with memory clobber.
__global__ __launch_bounds__(256) void dual_mfma32(
    const unsigned short* __restrict__ img,
    float* __restrict__ hi0, unsigned short* __restrict__ lo0,
    const unsigned short* __restrict__ AF)
{
    const int RS = 16 * 264;
    int n = blockIdx.x & 7;
    int q = blockIdx.x >> 3;
    int xseg = q & 15, yq = q >> 4;
    int t = threadIdx.x, wv = t >> 6, l = t & 63;
    int j = l & 31, pg = j >> 4, c = j & 15, kb = (l >> 5) * 8, hi = l >> 5;
    int x0 = xseg * 16;
    int pbase = (yq * 4 + wv) * 2;

    short8v A[10];
    #pragma unroll
    for (int i = 0; i < 10; ++i)
        A[i] = *(const short8v*)(AF + ((size_t)((9 + i) * 64 + l)) * 8);

    #pragma unroll 1
    for (int rep = 0; rep < 8; ++rep) {
        asm volatile("" ::: "memory");
        #pragma unroll
        for (int tp = 0; tp < 2; ++tp) {
            int y = (pbase + tp) * 2;
            const unsigned short* base =
                img + ((size_t)(n * 264 + y) * 16 + c) * 264 + x0 + pg * 8 + kb;
            f32x16 acc = {};
            #pragma unroll
            for (int i = 0; i < 10; ++i) {
                short8v B = *(const short8v*)(base + (size_t)i * RS);
                acc = MFMA32(A[i], B, acc, 0, 0, 0);
            }
            #pragma unroll
            for (int ry = 0; ry < 2; ++ry) {
                size_t hb = ((size_t)(n * 256 + y + ry) * 256 + x0 + pg * 8) * 16 + c;
                #pragma unroll
                for (int rr = 0; rr < 4; ++rr) {
                    int r = ry * 8 + rr;
                    int p = rr + 4 * hi;
                    nt_storef(hi0 + hb + (size_t)p * 16, acc[r]);
                }
                size_t lb = ((size_t)(n * 272 + y + ry + 8) * 16 + c) * 272
                            + (x0 + pg * 8 + 4 * hi + 8);
                int r0 = ry * 8 + 4;
                uint2 pk = make_uint2(pack2(acc[r0], acc[r0 + 1]),
                                      pack2(acc[r0 + 2], acc[r0 + 3]));
                *(uint2*)(lo0 + lb) = pk;
            }
        }
    }
}

// Fused per-scale (clamp-free), 2 tiles/wave fully unrolled.
// REP: diagnostic idempotent repeat count (8 for LOGW=8, else 1).
template <int LOGW, bool OUTF32, int REP>
__global__ __launch_bounds__(256) void scale_comb(
    const unsigned short* __restrict__ in,
    float* __restrict__ b0, float* __restrict__ b1,
    float* __restrict__ b2, float* __restrict__ b3,
    void* __restrict__ lo_out,
    const unsigned short* __restrict__ AF)
{
    const int W = 1 << LOGW, Wp = W + 16, XS = W / 16, RS = 16 * Wp;
    const int Wo = W >> 1, Wpo = Wo + 16, XS2 = Wo / 16;
    const int bandsPerN = XS * (W / 8);
    int n = blockIdx.x & 7;
    int q = blockIdx.x >> 3;
    int t = threadIdx.x, wv = t >> 6, l = t & 63;

    if (q < bandsPerN) {
        int xseg = q & (XS - 1), yq = q >> (LOGW - 4);
        int j = l & 31, pg = j >> 4, c = j & 15, kb = (l >> 5) * 8, hi = l >> 5;
        int x0 = xseg * 16;
        int ybase = (yq * 4 + wv) * 2;

        short8v A[9];
        #pragma unroll
        for (int dy = 0; dy < 9; ++dy)
            A[dy] = *(const short8v*)(AF + ((size_t)(dy * 64 + l)) * 8);

        #pragma unroll 1
        for (int rep = 0; rep < REP; ++rep) {
            asm volatile("" ::: "memory");
            #pragma unroll
            for (int ty = 0; ty < 2; ++ty) {
                int y = ybase + ty;
                const unsigned short* base =
                    in + ((size_t)(n * Wp + y + 4) * 16 + c) * Wp + x0 + pg * 8 + kb + 4;
                f32x16 acc = {};
                #pragma unroll
                for (int dy = 0; dy < 9; ++dy) {
                    short8v B = *(const short8v*)(base + (size_t)dy * RS);
                    acc = MFMA32(A[dy], B, acc, 0, 0, 0);
                }
                size_t ob = ((size_t)(n * W + y) * W + x0 + pg * 8) * 16 + c;
                #pragma unroll
                for (int rr = 0; rr < 4; ++rr) {
                    size_t o = ob + (size_t)(rr + 4 * hi) * 16;
                    nt_storef(b0 + o, acc[rr]);
                    nt_storef(b1 + o, acc[4 + rr]);
                    nt_storef(b2 + o, acc[8 + rr]);
                    nt_storef(b3 + o, acc[12 + rr]);
                }
            }
        }
    } else {
        int q2 = q - bandsPerN;
        int xseg = q2 & (XS2 - 1), yq = q2 >> (LOGW - 5);
        int m = l & 15, g = l >> 4, kb = g * 8;
        int x0 = xseg * 16;
        int ybase = (yq * 4 + wv) * 2;
        int off2 = (g < 2) ? 32 : 0;

        short8v A1[17], A2[17];
        #pragma unroll
        for (int dy = 0; dy < 17; ++dy) {
            A1[dy] = *(const short8v*)(AF + ((size_t)((19 + dy) * 64 + l)) * 8);
            A2[dy] = *(const short8v*)(AF + ((size_t)((36 + dy) * 64 + l)) * 8);
        }

        #pragma unroll 1
        for (int rep = 0; rep < REP; ++rep) {
            asm volatile("" ::: "memory");
            #pragma unroll
            for (int ty = 0; ty < 2; ++ty) {
                int yo = ybase + ty;
                const unsigned short* base =
                    in + ((size_t)(n * Wp + 2 * yo) * 16 + m) * Wp + 2 * x0 + kb;
                f32x4 aA = {0, 0, 0, 0}, aB = {0, 0, 0, 0};
                #pragma unroll
                for (int dy = 0; dy < 17; ++dy) {
                    short8v B1 = *(const short8v*)(base + (size_t)dy * RS);
                    short8v B2 = *(const short8v*)(base + (size_t)dy * RS + off2);
                    aA = MFMA16(A1[dy], B1, aA, 0, 0, 0);
                    aB = MFMA16(A2[dy], B2, aB, 0, 0, 0);
                }
                f32x4 acc = aA + aB;
                if (OUTF32) {
                    float* o = (float*)lo_out;
                    size_t ob = ((size_t)(n * Wo + yo) * Wo + x0 + g * 4) * 16 + m;
                    #pragma unroll
                    for (int r = 0; r < 4; ++r) nt_storef(o + ob + (size_t)r * 16, acc[r]);
                } else {
                    unsigned short* o = (unsigned short*)lo_out;
                    size_t lb = ((size_t)(n * Wpo + yo + 8) * 16 + m) * Wpo + (x0 + 8 + g * 4);
                    uint2 pk = make_uint2(pack2(acc[0], acc[1]),
                                          pack2(acc[2], acc[3]));
                    *(uint2*)(o + lb) = pk;
                }
            }
        }
    }
}

// ---------------------------------------------------------------- launch

extern "C" void kernel_launch(void* const* d_in, const int* in_sizes, int n_in,
                              void* d_out, int out_size, void* d_ws, size_t ws_size,
                              hipStream_t stream) {
    const float* image   = (const float*)d_in[0];
    const float* lo0filt = (const float*)d_in[1];
    const float* hi0filt = (const float*)d_in[2];
    const float* lofilt  = (const float*)d_in[3];
    const float* bfilts  = (const float*)d_in[4];
    float* out = (float*)d_out;

    const int N = 8, C = 16;
    size_t sz[5];
    const int Ws[5] = {256, 128, 64, 32, 16};
    for (int s = 0; s < 5; ++s) sz[s] = (size_t)N * Ws[s] * Ws[s] * C;

    // Workspace (ushort units): AF table, IMG CX (pad4), L0..L3 CX (pad8).
    unsigned short* wsu = (unsigned short*)d_ws;
    unsigned short* AF  = wsu;                       // 53*64*8 -> pad to 32768
    unsigned short* IMG = AF + 32768;
    unsigned short* L0 = IMG + (size_t)N * 264 * 16 * 264;
    unsigned short* L1 = L0 + (size_t)N * 272 * 16 * 272;
    unsigned short* L2 = L1 + (size_t)N * 144 * 16 * 144;
    unsigned short* L3 = L2 + (size_t)N * 80 * 16 * 80;

    // Output layout (reversed pyramid, flat):
    // [ lo_final | s=3 b=3..0 | s=2 b=3..0 | s=1 b=3..0 | s=0 b=3..0 | hi0 ]
    float* out_lofinal = out;
    size_t o = sz[4];
    float* band_ptr[4][4];
    for (int s = 3; s >= 0; --s)
        for (int b = 3; b >= 0; --b) { band_ptr[s][b] = out + o; o += sz[s]; }
    float* out_hi0 = out + o;

    prep_all<<<3150, 256, 0, stream>>>(
        bfilts, hi0filt, lo0filt, lofilt, AF, L0, L1, L2, L3,
        (const float4*)image, IMG);
    dual_mfma32<<<2048, 256, 0, stream>>>(IMG, out_hi0, L0, AF);
    scale_comb<8, false, 8><<<8 * (512 + 128), 256, 0, stream>>>(
        L0, band_ptr[0][0], band_ptr[0][1], band_ptr[0][2], band_ptr[0][3],
        (void*)L1, AF);
    scale_comb<7, false, 1><<<8 * (128 + 32), 256, 0, stream>>>(
        L1, band_ptr[1][0], band_ptr[1][1], band_ptr[1][2], band_ptr[1][3],
        (void*)L2, AF);
    scale_comb<6, false, 1><<<8 * (32 + 8), 256, 0, stream>>>(
        L2, band_ptr[2][0], band_ptr[2][1], band_ptr[2][2], band_ptr[2][3],
        (void*)L3, AF);
    scale_comb<5, true, 1><<<8 * (8 + 2), 256, 0, stream>>>(
        L3, band_ptr[3][0], band_ptr[3][1], band_ptr[3][2], band_ptr[3][3],
        (void*)out_lofinal, AF);
}

// Round 22
// 124.010 us; speedup vs baseline: 4.6577x; 4.6577x over previous
//
#include <hip/hip_runtime.h>

// Steerable pyramid via MFMA, fp32 I/O, bf16 compute (threshold = 2% of
// per-output absmax; bf16 error 16384 << 46202, verified r12-r21).
// CX layout for staged images: [n][y][c 16][x] bf16, zero-padded.
// Core (r15): 9-tap convs on mfma_f32_32x32x16_bf16 with fused M
// (bands: 4 bands x 8 px; dual: 2 rows x 2 filters x 8 px; K=16 window),
// down17 on 16x16x32 k-split. D map: col=l&31, row=(reg&3)+8(reg>>2)+4(l>>5).
// r21 diagnostic: store path was the stall (MfmaUtil 11%, VALU 3%, write
// BW 2.37 TB/s vs fill's 6.9; 4-segment scalar nt stores).
// r22: in-wave LDS micro-transpose (16px x 16ch per band, stride-20 rows,
// no barrier -- DS ops in-order per wave) -> ONE contiguous
// global_store_dwordx4 per lane per band (1KB/wave-instr, was 4x 256B
// 4-segment); nt dropped (cached stores complete in L2).

typedef __attribute__((ext_vector_type(8))) short short8v;
typedef __attribute__((ext_vector_type(4))) float f32x4;
typedef __attribute__((ext_vector_type(16))) float f32x16;

static __device__ __forceinline__ unsigned short f2bf(float f) {
    union { float f; unsigned u; } v; v.f = f;
    unsigned u = v.u;
    u += 0x7fffu + ((u >> 16) & 1u);
    return (unsigned short)(u >> 16);
}

static __device__ __forceinline__ unsigned pack2(float a, float b) {
    return (unsigned)f2bf(a) | ((unsigned)f2bf(b) << 16);
}

// AF fragment table rows (entry = short8v per lane, row*64+l):
// [0..8] bands32 dy | [9..18] dual32 i | [19..35] down A1 | [36..52] down A2

// ---------------------------------------------------------------- prep

static __device__ __forceinline__ void do_build_frags(
    const float* bf, const float* fh, const float* fl, const float* lfilt,
    unsigned short* AF, int id)
{
    if (id >= 53 * 64) return;
    int row = id >> 6, l = id & 63;
    short8v a;
    if (row < 9) {
        int dy = row;
        int m = l & 31, f = m >> 3, p = m & 7, kb = (l >> 5) * 8;
        #pragma unroll
        for (int i = 0; i < 8; ++i) {
            int d = kb + i - p;
            a[i] = (short)((d >= 0 && d < 9) ? f2bf(bf[f * 81 + dy * 9 + d]) : 0);
        }
    } else if (row < 19) {
        int is = row - 9;
        int m = l & 31, ry = m >> 4, f = (m >> 3) & 1, p = m & 7, kb = (l >> 5) * 8;
        int dy = is - ry;
        const float* fr = f ? fl : fh;
        #pragma unroll
        for (int i = 0; i < 8; ++i) {
            int dx = kb + i - p;
            bool ok = (dy >= 0 && dy < 9) && (dx >= 0 && dx < 9);
            a[i] = (short)(ok ? f2bf(fr[dy * 9 + dx]) : 0);
        }
    } else if (row < 36) {
        int dy = row - 19;
        int m = l & 15, kb = (l >> 4) * 8;
        #pragma unroll
        for (int i = 0; i < 8; ++i) {
            int d = kb + i - 2 * m;
            a[i] = (short)((d >= 0 && d < 17) ? f2bf(lfilt[dy * 17 + d]) : 0);
        }
    } else {
        int dy = row - 36;
        int m = l & 15, kb = (l >> 4) * 8;
        #pragma unroll
        for (int i = 0; i < 8; ++i) {
            int d = 32 + kb + i - 2 * m;
            a[i] = (short)((d >= 0 && d < 17) ? f2bf(lfilt[dy * 17 + d]) : 0);
        }
    }
    *(short8v*)(AF + (size_t)id * 8) = a;
}

static __device__ __forceinline__ void zero_cx_vec(
    unsigned short* buf, int W, int id)
{
    int Wp = W + 16, Wv = Wp >> 3;
    int rowT = 16 * 16 * Wv;
    int perN = rowT + W * 32;
    int n = id / perN;
    int r = id - n * perN;
    int y, c, xv;
    if (r < rowT) {
        int ry = r / (16 * Wv);
        int rem = r - ry * (16 * Wv);
        c = rem / Wv;
        xv = rem - c * Wv;
        y = (ry < 8) ? ry : ry + W;
    } else {
        int r2 = r - rowT;
        y = 8 + (r2 >> 5);
        int rem = r2 & 31;
        c = rem >> 1;
        xv = (rem & 1) ? (Wv - 1) : 0;
    }
    short8v z = {0, 0, 0, 0, 0, 0, 0, 0};
    *(short8v*)(buf + ((size_t)(n * Wp + y) * 16 + c) * Wp + xv * 8) = z;
}

// prep_all: [0,14) build_frags | [14,1038) zero_pads | [1038,3150) img_to_cx.
__global__ __launch_bounds__(256) void prep_all(
    const float* __restrict__ bf, const float* __restrict__ fh,
    const float* __restrict__ fl, const float* __restrict__ lfilt,
    unsigned short* __restrict__ AF,
    unsigned short* __restrict__ L0, unsigned short* __restrict__ L1,
    unsigned short* __restrict__ L2, unsigned short* __restrict__ L3,
    const float4* __restrict__ src4, unsigned short* __restrict__ IMG)
{
    __shared__ unsigned short lds[16][264];
    int b = blockIdx.x, t = threadIdx.x;
    if (b < 14) {
        do_build_frags(bf, fh, fl, lfilt, AF, b * 256 + t);
    } else if (b < 1038) {
        int zb = b - 14;
        if (zb < 528)      zero_cx_vec(L0, 256, zb * 256 + t);
        else if (zb < 800) zero_cx_vec(L1, 128, (zb - 528) * 256 + t);
        else if (zb < 944) zero_cx_vec(L2, 64,  (zb - 800) * 256 + t);
        else               zero_cx_vec(L3, 32,  (zb - 944) * 256 + t);
    } else {
        int ib = b - 1038;                   // 2112 = 8 * 264
        int n = ib & 7;
        int yp = ib >> 3;
        int y = yp - 4;
        unsigned short* drow = IMG + ((size_t)(n * 264 + yp) * 16) * 264;
        if ((unsigned)y < 256u) {
            for (int task = t; task < 1056; task += 256) {
                int px = task >> 2, cg = task & 3;
                int xs = px - 4;
                bool ok = (unsigned)xs < 256u;
                int xc = min(max(xs, 0), 255);
                float4 v = src4[((size_t)(n * 256 + y) * 256 + xc) * 4 + cg];
                lds[cg * 4 + 0][px] = (unsigned short)(ok ? f2bf(v.x) : 0);
                lds[cg * 4 + 1][px] = (unsigned short)(ok ? f2bf(v.y) : 0);
                lds[cg * 4 + 2][px] = (unsigned short)(ok ? f2bf(v.z) : 0);
                lds[cg * 4 + 3][px] = (unsigned short)(ok ? f2bf(v.w) : 0);
            }
            __syncthreads();
            for (int task = t; task < 528; task += 256) {
                int c = task / 33, xg = task - c * 33;
                short8v v = *(const short8v*)&lds[c][xg * 8];
                *(short8v*)(drow + (size_t)c * 264 + xg * 8) = v;
            }
        } else {
            short8v z = {0, 0, 0, 0, 0, 0, 0, 0};
            for (int task = t; task < 528; task += 256) {
                int c = task / 33, xg = task - c * 33;
                *(short8v*)(drow + (size_t)c * 264 + xg * 8) = z;
            }
        }
    }
}

// ---------------------------------------------------------------- MFMA convs

#define MFMA16 __builtin_amdgcn_mfma_f32_16x16x32_bf16
#define MFMA32 __builtin_amdgcn_mfma_f32_32x32x16_bf16

// hi0 + lo0 from IMG CX (pad 4), 32x32x16, M = 2 rows x 2 filt x 8 px.
// hi0 stores via in-wave LDS transpose -> contiguous dwordx4.
__global__ __launch_bounds__(256) void dual_mfma32(
    const unsigned short* __restrict__ img,
    float* __restrict__ hi0, unsigned short* __restrict__ lo0,
    const unsigned short* __restrict__ AF)
{
    const int RS = 16 * 264;
    __shared__ float tr[4][320];
    int n = blockIdx.x & 7;
    int q = blockIdx.x >> 3;
    int xseg = q & 15, yq = q >> 4;
    int t = threadIdx.x, wv = t >> 6, l = t & 63;
    int j = l & 31, pg = j >> 4, c = j & 15, kb = (l >> 5) * 8, hi = l >> 5;
    int x0 = xseg * 16;
    int pbase = (yq * 4 + wv) * 2;
    float* T = tr[wv];
    int wbase = (pg * 8 + 4 * hi) * 20 + c;
    int rdoff = (l >> 2) * 20 + (l & 3) * 4;
    int soff  = (l >> 2) * 16 + (l & 3) * 4;

    short8v A[10];
    #pragma unroll
    for (int i = 0; i < 10; ++i)
        A[i] = *(const short8v*)(AF + ((size_t)((9 + i) * 64 + l)) * 8);

    #pragma unroll
    for (int tp = 0; tp < 2; ++tp) {
        int y = (pbase + tp) * 2;
        const unsigned short* base =
            img + ((size_t)(n * 264 + y) * 16 + c) * 264 + x0 + pg * 8 + kb;
        f32x16 acc = {};
        #pragma unroll
        for (int i = 0; i < 10; ++i) {
            short8v B = *(const short8v*)(base + (size_t)i * RS);
            acc = MFMA32(A[i], B, acc, 0, 0, 0);
        }
        #pragma unroll
        for (int ry = 0; ry < 2; ++ry) {
            // hi0: transpose 16px x 16c in-wave, one dwordx4 per lane
            T[wbase]      = acc[ry * 8 + 0];
            T[wbase + 20] = acc[ry * 8 + 1];
            T[wbase + 40] = acc[ry * 8 + 2];
            T[wbase + 60] = acc[ry * 8 + 3];
            size_t so = ((size_t)(n * 256 + y + ry) * 256 + x0) * 16 + soff;
            *(float4*)(hi0 + so) = *(const float4*)&T[rdoff];
            // lo0 bf16 CX (small traffic, unchanged)
            size_t lb = ((size_t)(n * 272 + y + ry + 8) * 16 + c) * 272
                        + (x0 + pg * 8 + 4 * hi + 8);
            int r0 = ry * 8 + 4;
            uint2 pk = make_uint2(pack2(acc[r0], acc[r0 + 1]),
                                  pack2(acc[r0 + 2], acc[r0 + 3]));
            *(uint2*)(lo0 + lb) = pk;
        }
    }
}

// Fused per-scale (clamp-free), 2 tiles/wave fully unrolled.
// Bands stores via in-wave LDS transpose -> contiguous dwordx4 per band.
template <int LOGW, bool OUTF32>
__global__ __launch_bounds__(256) void scale_comb(
    const unsigned short* __restrict__ in,
    float* __restrict__ b0, float* __restrict__ b1,
    float* __restrict__ b2, float* __restrict__ b3,
    void* __restrict__ lo_out,
    const unsigned short* __restrict__ AF)
{
    const int W = 1 << LOGW, Wp = W + 16, XS = W / 16, RS = 16 * Wp;
    const int Wo = W >> 1, Wpo = Wo + 16, XS2 = Wo / 16;
    const int bandsPerN = XS * (W / 8);
    __shared__ float tr[4][320];
    int n = blockIdx.x & 7;
    int q = blockIdx.x >> 3;
    int t = threadIdx.x, wv = t >> 6, l = t & 63;

    if (q < bandsPerN) {
        int xseg = q & (XS - 1), yq = q >> (LOGW - 4);
        int j = l & 31, pg = j >> 4, c = j & 15, kb = (l >> 5) * 8, hi = l >> 5;
        int x0 = xseg * 16;
        int ybase = (yq * 4 + wv) * 2;
        float* T = tr[wv];
        int wbase = (pg * 8 + 4 * hi) * 20 + c;
        int rdoff = (l >> 2) * 20 + (l & 3) * 4;
        int soff  = (l >> 2) * 16 + (l & 3) * 4;

        short8v A[9];
        #pragma unroll
        for (int dy = 0; dy < 9; ++dy)
            A[dy] = *(const short8v*)(AF + ((size_t)(dy * 64 + l)) * 8);

        #pragma unroll
        for (int ty = 0; ty < 2; ++ty) {
            int y = ybase + ty;
            const unsigned short* base =
                in + ((size_t)(n * Wp + y + 4) * 16 + c) * Wp + x0 + pg * 8 + kb + 4;
            f32x16 acc = {};
            #pragma unroll
            for (int dy = 0; dy < 9; ++dy) {
                short8v B = *(const short8v*)(base + (size_t)dy * RS);
                acc = MFMA32(A[dy], B, acc, 0, 0, 0);
            }
            size_t so = ((size_t)(n * W + y) * W + x0) * 16 + soff;
            // band 0
            T[wbase] = acc[0];  T[wbase + 20] = acc[1];
            T[wbase + 40] = acc[2]; T[wbase + 60] = acc[3];
            *(float4*)(b0 + so) = *(const float4*)&T[rdoff];
            // band 1
            T[wbase] = acc[4];  T[wbase + 20] = acc[5];
            T[wbase + 40] = acc[6]; T[wbase + 60] = acc[7];
            *(float4*)(b1 + so) = *(const float4*)&T[rdoff];
            // band 2
            T[wbase] = acc[8];  T[wbase + 20] = acc[9];
            T[wbase + 40] = acc[10]; T[wbase + 60] = acc[11];
            *(float4*)(b2 + so) = *(const float4*)&T[rdoff];
            // band 3
            T[wbase] = acc[12]; T[wbase + 20] = acc[13];
            T[wbase + 40] = acc[14]; T[wbase + 60] = acc[15];
            *(float4*)(b3 + so) = *(const float4*)&T[rdoff];
        }
    } else {
        int q2 = q - bandsPerN;
        int xseg = q2 & (XS2 - 1), yq = q2 >> (LOGW - 5);
        int m = l & 15, g = l >> 4, kb = g * 8;
        int x0 = xseg * 16;
        int ybase = (yq * 4 + wv) * 2;
        int off2 = (g < 2) ? 32 : 0;

        short8v A1[17], A2[17];
        #pragma unroll
        for (int dy = 0; dy < 17; ++dy) {
            A1[dy] = *(const short8v*)(AF + ((size_t)((19 + dy) * 64 + l)) * 8);
            A2[dy] = *(const short8v*)(AF + ((size_t)((36 + dy) * 64 + l)) * 8);
        }

        #pragma unroll
        for (int ty = 0; ty < 2; ++ty) {
            int yo = ybase + ty;
            const unsigned short* base =
                in + ((size_t)(n * Wp + 2 * yo) * 16 + m) * Wp + 2 * x0 + kb;
            f32x4 aA = {0, 0, 0, 0}, aB = {0, 0, 0, 0};
            #pragma unroll
            for (int dy = 0; dy < 17; ++dy) {
                short8v B1 = *(const short8v*)(base + (size_t)dy * RS);
                short8v B2 = *(const short8v*)(base + (size_t)dy * RS + off2);
                aA = MFMA16(A1[dy], B1, aA, 0, 0, 0);
                aB = MFMA16(A2[dy], B2, aB, 0, 0, 0);
            }
            f32x4 acc = aA + aB;
            if (OUTF32) {
                float* o = (float*)lo_out;
                size_t ob = ((size_t)(n * Wo + yo) * Wo + x0 + g * 4) * 16 + m;
                #pragma unroll
                for (int r = 0; r < 4; ++r) o[ob + (size_t)r * 16] = acc[r];
            } else {
                unsigned short* o = (unsigned short*)lo_out;
                size_t lb = ((size_t)(n * Wpo + yo + 8) * 16 + m) * Wpo + (x0 + 8 + g * 4);
                uint2 pk = make_uint2(pack2(acc[0], acc[1]),
                                      pack2(acc[2], acc[3]));
                *(uint2*)(o + lb) = pk;
            }
        }
    }
}

// ---------------------------------------------------------------- launch

extern "C" void kernel_launch(void* const* d_in, const int* in_sizes, int n_in,
                              void* d_out, int out_size, void* d_ws, size_t ws_size,
                              hipStream_t stream) {
    const float* image   = (const float*)d_in[0];
    const float* lo0filt = (const float*)d_in[1];
    const float* hi0filt = (const float*)d_in[2];
    const float* lofilt  = (const float*)d_in[3];
    const float* bfilts  = (const float*)d_in[4];
    float* out = (float*)d_out;

    const int N = 8, C = 16;
    size_t sz[5];
    const int Ws[5] = {256, 128, 64, 32, 16};
    for (int s = 0; s < 5; ++s) sz[s] = (size_t)N * Ws[s] * Ws[s] * C;

    // Workspace (ushort units): AF table, IMG CX (pad4), L0..L3 CX (pad8).
    unsigned short* wsu = (unsigned short*)d_ws;
    unsigned short* AF  = wsu;                       // 53*64*8 -> pad to 32768
    unsigned short* IMG = AF + 32768;
    unsigned short* L0 = IMG + (size_t)N * 264 * 16 * 264;
    unsigned short* L1 = L0 + (size_t)N * 272 * 16 * 272;
    unsigned short* L2 = L1 + (size_t)N * 144 * 16 * 144;
    unsigned short* L3 = L2 + (size_t)N * 80 * 16 * 80;

    // Output layout (reversed pyramid, flat):
    // [ lo_final | s=3 b=3..0 | s=2 b=3..0 | s=1 b=3..0 | s=0 b=3..0 | hi0 ]
    float* out_lofinal = out;
    size_t o = sz[4];
    float* band_ptr[4][4];
    for (int s = 3; s >= 0; --s)
        for (int b = 3; b >= 0; --b) { band_ptr[s][b] = out + o; o += sz[s]; }
    float* out_hi0 = out + o;

    prep_all<<<3150, 256, 0, stream>>>(
        bfilts, hi0filt, lo0filt, lofilt, AF, L0, L1, L2, L3,
        (const float4*)image, IMG);
    dual_mfma32<<<2048, 256, 0, stream>>>(IMG, out_hi0, L0, AF);
    scale_comb<8, false><<<8 * (512 + 128), 256, 0, stream>>>(
        L0, band_ptr[0][0], band_ptr[0][1], band_ptr[0][2], band_ptr[0][3],
        (void*)L1, AF);
    scale_comb<7, false><<<8 * (128 + 32), 256, 0, stream>>>(
        L1, band_ptr[1][0], band_ptr[1][1], band_ptr[1][2], band_ptr[1][3],
        (void*)L2, AF);
    scale_comb<6, false><<<8 * (32 + 8), 256, 0, stream>>>(
        L2, band_ptr[2][0], band_ptr[2][1], band_ptr[2][2], band_ptr[2][3],
        (void*)L3, AF);
    scale_comb<5, true><<<8 * (8 + 2), 256, 0, stream>>>(
        L3, band_ptr[3][0], band_ptr[3][1], band_ptr[3][2], band_ptr[3][3],
        (void*)out_lofinal, AF);
}

// Round 23
// 117.845 us; speedup vs baseline: 4.9013x; 1.0523x over previous
//
#include <hip/hip_runtime.h>

// Steerable pyramid via MFMA, fp32 I/O, bf16 compute (threshold = 2% of
// per-output absmax; bf16 error ~16384 << 46202, verified r12-r22).
// CX layout for staged images: [n][y][c 16][x] bf16, zero-padded.
// Core (r15): 9-tap convs on mfma_f32_32x32x16_bf16 with fused M
// (bands: 4 bands x 8 px; dual: 2 rows x 2 filters x 8 px; K=16 window),
// down17 on 16x16x32 k-split. D map: col=l&31, row=(reg&3)+8(reg>>2)+4(l>>5).
// r22 lesson: LDS store-transpose serializes (per-band RAW through one
// T buffer) -> reverted; r21 diagnostic was store-regime-distorted.
// r23 = r20 (best, 116.8us) + SPLIT MFMA CHAINS: each tile's serial
// 9-10 MFMA dependency chain becomes two even/odd-dy chains (+16 VGPR,
// same 3 waves/SIMD) summed by one VALU vector add -> 2x in-wave MFMA
// ILP to cover the ~40cy MFMA latency.

typedef __attribute__((ext_vector_type(8))) short short8v;
typedef __attribute__((ext_vector_type(4))) float f32x4;
typedef __attribute__((ext_vector_type(16))) float f32x16;

static __device__ __forceinline__ unsigned short f2bf(float f) {
    union { float f; unsigned u; } v; v.f = f;
    unsigned u = v.u;
    u += 0x7fffu + ((u >> 16) & 1u);
    return (unsigned short)(u >> 16);
}

static __device__ __forceinline__ unsigned pack2(float a, float b) {
    return (unsigned)f2bf(a) | ((unsigned)f2bf(b) << 16);
}

static __device__ __forceinline__ void nt_storef(float* p, float v) {
    __builtin_nontemporal_store(v, p);
}

// AF fragment table rows (entry = short8v per lane, row*64+l):
// [0..8] bands32 dy | [9..18] dual32 i | [19..35] down A1 | [36..52] down A2

// ---------------------------------------------------------------- prep

static __device__ __forceinline__ void do_build_frags(
    const float* bf, const float* fh, const float* fl, const float* lfilt,
    unsigned short* AF, int id)
{
    if (id >= 53 * 64) return;
    int row = id >> 6, l = id & 63;
    short8v a;
    if (row < 9) {
        int dy = row;
        int m = l & 31, f = m >> 3, p = m & 7, kb = (l >> 5) * 8;
        #pragma unroll
        for (int i = 0; i < 8; ++i) {
            int d = kb + i - p;
            a[i] = (short)((d >= 0 && d < 9) ? f2bf(bf[f * 81 + dy * 9 + d]) : 0);
        }
    } else if (row < 19) {
        int is = row - 9;
        int m = l & 31, ry = m >> 4, f = (m >> 3) & 1, p = m & 7, kb = (l >> 5) * 8;
        int dy = is - ry;
        const float* fr = f ? fl : fh;
        #pragma unroll
        for (int i = 0; i < 8; ++i) {
            int dx = kb + i - p;
            bool ok = (dy >= 0 && dy < 9) && (dx >= 0 && dx < 9);
            a[i] = (short)(ok ? f2bf(fr[dy * 9 + dx]) : 0);
        }
    } else if (row < 36) {
        int dy = row - 19;
        int m = l & 15, kb = (l >> 4) * 8;
        #pragma unroll
        for (int i = 0; i < 8; ++i) {
            int d = kb + i - 2 * m;
            a[i] = (short)((d >= 0 && d < 17) ? f2bf(lfilt[dy * 17 + d]) : 0);
        }
    } else {
        int dy = row - 36;
        int m = l & 15, kb = (l >> 4) * 8;
        #pragma unroll
        for (int i = 0; i < 8; ++i) {
            int d = 32 + kb + i - 2 * m;
            a[i] = (short)((d >= 0 && d < 17) ? f2bf(lfilt[dy * 17 + d]) : 0);
        }
    }
    *(short8v*)(AF + (size_t)id * 8) = a;
}

static __device__ __forceinline__ void zero_cx_vec(
    unsigned short* buf, int W, int id)
{
    int Wp = W + 16, Wv = Wp >> 3;
    int rowT = 16 * 16 * Wv;
    int perN = rowT + W * 32;
    int n = id / perN;
    int r = id - n * perN;
    int y, c, xv;
    if (r < rowT) {
        int ry = r / (16 * Wv);
        int rem = r - ry * (16 * Wv);
        c = rem / Wv;
        xv = rem - c * Wv;
        y = (ry < 8) ? ry : ry + W;
    } else {
        int r2 = r - rowT;
        y = 8 + (r2 >> 5);
        int rem = r2 & 31;
        c = rem >> 1;
        xv = (rem & 1) ? (Wv - 1) : 0;
    }
    short8v z = {0, 0, 0, 0, 0, 0, 0, 0};
    *(short8v*)(buf + ((size_t)(n * Wp + y) * 16 + c) * Wp + xv * 8) = z;
}

// prep_all: [0,14) build_frags | [14,1038) zero_pads | [1038,3150) img_to_cx.
__global__ __launch_bounds__(256) void prep_all(
    const float* __restrict__ bf, const float* __restrict__ fh,
    const float* __restrict__ fl, const float* __restrict__ lfilt,
    unsigned short* __restrict__ AF,
    unsigned short* __restrict__ L0, unsigned short* __restrict__ L1,
    unsigned short* __restrict__ L2, unsigned short* __restrict__ L3,
    const float4* __restrict__ src4, unsigned short* __restrict__ IMG)
{
    __shared__ unsigned short lds[16][264];
    int b = blockIdx.x, t = threadIdx.x;
    if (b < 14) {
        do_build_frags(bf, fh, fl, lfilt, AF, b * 256 + t);
    } else if (b < 1038) {
        int zb = b - 14;
        if (zb < 528)      zero_cx_vec(L0, 256, zb * 256 + t);
        else if (zb < 800) zero_cx_vec(L1, 128, (zb - 528) * 256 + t);
        else if (zb < 944) zero_cx_vec(L2, 64,  (zb - 800) * 256 + t);
        else               zero_cx_vec(L3, 32,  (zb - 944) * 256 + t);
    } else {
        int ib = b - 1038;                   // 2112 = 8 * 264
        int n = ib & 7;
        int yp = ib >> 3;
        int y = yp - 4;
        unsigned short* drow = IMG + ((size_t)(n * 264 + yp) * 16) * 264;
        if ((unsigned)y < 256u) {
            for (int task = t; task < 1056; task += 256) {
                int px = task >> 2, cg = task & 3;
                int xs = px - 4;
                bool ok = (unsigned)xs < 256u;
                int xc = min(max(xs, 0), 255);
                float4 v = src4[((size_t)(n * 256 + y) * 256 + xc) * 4 + cg];
                lds[cg * 4 + 0][px] = (unsigned short)(ok ? f2bf(v.x) : 0);
                lds[cg * 4 + 1][px] = (unsigned short)(ok ? f2bf(v.y) : 0);
                lds[cg * 4 + 2][px] = (unsigned short)(ok ? f2bf(v.z) : 0);
                lds[cg * 4 + 3][px] = (unsigned short)(ok ? f2bf(v.w) : 0);
            }
            __syncthreads();
            for (int task = t; task < 528; task += 256) {
                int c = task / 33, xg = task - c * 33;
                short8v v = *(const short8v*)&lds[c][xg * 8];
                *(short8v*)(drow + (size_t)c * 264 + xg * 8) = v;
            }
        } else {
            short8v z = {0, 0, 0, 0, 0, 0, 0, 0};
            for (int task = t; task < 528; task += 256) {
                int c = task / 33, xg = task - c * 33;
                *(short8v*)(drow + (size_t)c * 264 + xg * 8) = z;
            }
        }
    }
}

// ---------------------------------------------------------------- MFMA convs

#define MFMA16 __builtin_amdgcn_mfma_f32_16x16x32_bf16
#define MFMA32 __builtin_amdgcn_mfma_f32_32x32x16_bf16

// hi0 + lo0 from IMG CX (pad 4), 32x32x16, M = 2 rows x 2 filt x 8 px.
// 2 tiles/wave fully unrolled; 2 MFMA chains per tile (even/odd i).
__global__ __launch_bounds__(256) void dual_mfma32(
    const unsigned short* __restrict__ img,
    float* __restrict__ hi0, unsigned short* __restrict__ lo0,
    const unsigned short* __restrict__ AF)
{
    const int RS = 16 * 264;
    int n = blockIdx.x & 7;
    int q = blockIdx.x >> 3;
    int xseg = q & 15, yq = q >> 4;
    int t = threadIdx.x, wv = t >> 6, l = t & 63;
    int j = l & 31, pg = j >> 4, c = j & 15, kb = (l >> 5) * 8, hi = l >> 5;
    int x0 = xseg * 16;
    int pbase = (yq * 4 + wv) * 2;

    short8v A[10];
    #pragma unroll
    for (int i = 0; i < 10; ++i)
        A[i] = *(const short8v*)(AF + ((size_t)((9 + i) * 64 + l)) * 8);

    #pragma unroll
    for (int tp = 0; tp < 2; ++tp) {
        int y = (pbase + tp) * 2;
        const unsigned short* base =
            img + ((size_t)(n * 264 + y) * 16 + c) * 264 + x0 + pg * 8 + kb;
        f32x16 accA = {}, accB = {};
        #pragma unroll
        for (int i = 0; i < 10; i += 2) {
            short8v B0 = *(const short8v*)(base + (size_t)i * RS);
            short8v B1 = *(const short8v*)(base + (size_t)(i + 1) * RS);
            accA = MFMA32(A[i], B0, accA, 0, 0, 0);
            accB = MFMA32(A[i + 1], B1, accB, 0, 0, 0);
        }
        f32x16 acc = accA + accB;
        #pragma unroll
        for (int ry = 0; ry < 2; ++ry) {
            size_t hb = ((size_t)(n * 256 + y + ry) * 256 + x0 + pg * 8) * 16 + c;
            #pragma unroll
            for (int rr = 0; rr < 4; ++rr) {
                int r = ry * 8 + rr;
                int p = rr + 4 * hi;
                nt_storef(hi0 + hb + (size_t)p * 16, acc[r]);
            }
            size_t lb = ((size_t)(n * 272 + y + ry + 8) * 16 + c) * 272
                        + (x0 + pg * 8 + 4 * hi + 8);
            int r0 = ry * 8 + 4;
            uint2 pk = make_uint2(pack2(acc[r0], acc[r0 + 1]),
                                  pack2(acc[r0 + 2], acc[r0 + 3]));
            *(uint2*)(lo0 + lb) = pk;
        }
    }
}

// Fused per-scale (clamp-free), 2 tiles/wave fully unrolled.
// Bands: 2 chains (even/odd dy, 5+4). Down: 4 chains (aA/aB x even/odd).
template <int LOGW, bool OUTF32>
__global__ __launch_bounds__(256) void scale_comb(
    const unsigned short* __restrict__ in,
    float* __restrict__ b0, float* __restrict__ b1,
    float* __restrict__ b2, float* __restrict__ b3,
    void* __restrict__ lo_out,
    const unsigned short* __restrict__ AF)
{
    const int W = 1 << LOGW, Wp = W + 16, XS = W / 16, RS = 16 * Wp;
    const int Wo = W >> 1, Wpo = Wo + 16, XS2 = Wo / 16;
    const int bandsPerN = XS * (W / 8);
    int n = blockIdx.x & 7;
    int q = blockIdx.x >> 3;
    int t = threadIdx.x, wv = t >> 6, l = t & 63;

    if (q < bandsPerN) {
        int xseg = q & (XS - 1), yq = q >> (LOGW - 4);
        int j = l & 31, pg = j >> 4, c = j & 15, kb = (l >> 5) * 8, hi = l >> 5;
        int x0 = xseg * 16;
        int ybase = (yq * 4 + wv) * 2;

        short8v A[9];
        #pragma unroll
        for (int dy = 0; dy < 9; ++dy)
            A[dy] = *(const short8v*)(AF + ((size_t)(dy * 64 + l)) * 8);

        #pragma unroll
        for (int ty = 0; ty < 2; ++ty) {
            int y = ybase + ty;
            const unsigned short* base =
                in + ((size_t)(n * Wp + y + 4) * 16 + c) * Wp + x0 + pg * 8 + kb + 4;
            f32x16 accA = {}, accB = {};
            #pragma unroll
            for (int dy = 0; dy < 8; dy += 2) {
                short8v B0 = *(const short8v*)(base + (size_t)dy * RS);
                short8v B1 = *(const short8v*)(base + (size_t)(dy + 1) * RS);
                accA = MFMA32(A[dy], B0, accA, 0, 0, 0);
                accB = MFMA32(A[dy + 1], B1, accB, 0, 0, 0);
            }
            {
                short8v B8 = *(const short8v*)(base + (size_t)8 * RS);
                accA = MFMA32(A[8], B8, accA, 0, 0, 0);
            }
            f32x16 acc = accA + accB;
            size_t ob = ((size_t)(n * W + y) * W + x0 + pg * 8) * 16 + c;
            #pragma unroll
            for (int rr = 0; rr < 4; ++rr) {
                size_t o = ob + (size_t)(rr + 4 * hi) * 16;
                nt_storef(b0 + o, acc[rr]);
                nt_storef(b1 + o, acc[4 + rr]);
                nt_storef(b2 + o, acc[8 + rr]);
                nt_storef(b3 + o, acc[12 + rr]);
            }
        }
    } else {
        int q2 = q - bandsPerN;
        int xseg = q2 & (XS2 - 1), yq = q2 >> (LOGW - 5);
        int m = l & 15, g = l >> 4, kb = g * 8;
        int x0 = xseg * 16;
        int ybase = (yq * 4 + wv) * 2;
        int off2 = (g < 2) ? 32 : 0;

        short8v A1[17], A2[17];
        #pragma unroll
        for (int dy = 0; dy < 17; ++dy) {
            A1[dy] = *(const short8v*)(AF + ((size_t)((19 + dy) * 64 + l)) * 8);
            A2[dy] = *(const short8v*)(AF + ((size_t)((36 + dy) * 64 + l)) * 8);
        }

        #pragma unroll
        for (int ty = 0; ty < 2; ++ty) {
            int yo = ybase + ty;
            const unsigned short* base =
                in + ((size_t)(n * Wp + 2 * yo) * 16 + m) * Wp + 2 * x0 + kb;
            f32x4 aA0 = {0, 0, 0, 0}, aA1 = {0, 0, 0, 0};
            f32x4 aB0 = {0, 0, 0, 0}, aB1 = {0, 0, 0, 0};
            #pragma unroll
            for (int dy = 0; dy < 16; dy += 2) {
                short8v B1a = *(const short8v*)(base + (size_t)dy * RS);
                short8v B2a = *(const short8v*)(base + (size_t)dy * RS + off2);
                short8v B1b = *(const short8v*)(base + (size_t)(dy + 1) * RS);
                short8v B2b = *(const short8v*)(base + (size_t)(dy + 1) * RS + off2);
                aA0 = MFMA16(A1[dy], B1a, aA0, 0, 0, 0);
                aB0 = MFMA16(A2[dy], B2a, aB0, 0, 0, 0);
                aA1 = MFMA16(A1[dy + 1], B1b, aA1, 0, 0, 0);
                aB1 = MFMA16(A2[dy + 1], B2b, aB1, 0, 0, 0);
            }
            {
                short8v B1a = *(const short8v*)(base + (size_t)16 * RS);
                short8v B2a = *(const short8v*)(base + (size_t)16 * RS + off2);
                aA0 = MFMA16(A1[16], B1a, aA0, 0, 0, 0);
                aB0 = MFMA16(A2[16], B2a, aB0, 0, 0, 0);
            }
            f32x4 acc = (aA0 + aA1) + (aB0 + aB1);
            if (OUTF32) {
                float* o = (float*)lo_out;
                size_t ob = ((size_t)(n * Wo + yo) * Wo + x0 + g * 4) * 16 + m;
                #pragma unroll
                for (int r = 0; r < 4; ++r) nt_storef(o + ob + (size_t)r * 16, acc[r]);
            } else {
                unsigned short* o = (unsigned short*)lo_out;
                size_t lb = ((size_t)(n * Wpo + yo + 8) * 16 + m) * Wpo + (x0 + 8 + g * 4);
                uint2 pk = make_uint2(pack2(acc[0], acc[1]),
                                      pack2(acc[2], acc[3]));
                *(uint2*)(o + lb) = pk;
            }
        }
    }
}

// ---------------------------------------------------------------- launch

extern "C" void kernel_launch(void* const* d_in, const int* in_sizes, int n_in,
                              void* d_out, int out_size, void* d_ws, size_t ws_size,
                              hipStream_t stream) {
    const float* image   = (const float*)d_in[0];
    const float* lo0filt = (const float*)d_in[1];
    const float* hi0filt = (const float*)d_in[2];
    const float* lofilt  = (const float*)d_in[3];
    const float* bfilts  = (const float*)d_in[4];
    float* out = (float*)d_out;

    const int N = 8, C = 16;
    size_t sz[5];
    const int Ws[5] = {256, 128, 64, 32, 16};
    for (int s = 0; s < 5; ++s) sz[s] = (size_t)N * Ws[s] * Ws[s] * C;

    // Workspace (ushort units): AF table, IMG CX (pad4), L0..L3 CX (pad8).
    unsigned short* wsu = (unsigned short*)d_ws;
    unsigned short* AF  = wsu;                       // 53*64*8 -> pad to 32768
    unsigned short* IMG = AF + 32768;
    unsigned short* L0 = IMG + (size_t)N * 264 * 16 * 264;
    unsigned short* L1 = L0 + (size_t)N * 272 * 16 * 272;
    unsigned short* L2 = L1 + (size_t)N * 144 * 16 * 144;
    unsigned short* L3 = L2 + (size_t)N * 80 * 16 * 80;

    // Output layout (reversed pyramid, flat):
    // [ lo_final | s=3 b=3..0 | s=2 b=3..0 | s=1 b=3..0 | s=0 b=3..0 | hi0 ]
    float* out_lofinal = out;
    size_t o = sz[4];
    float* band_ptr[4][4];
    for (int s = 3; s >= 0; --s)
        for (int b = 3; b >= 0; --b) { band_ptr[s][b] = out + o; o += sz[s]; }
    float* out_hi0 = out + o;

    prep_all<<<3150, 256, 0, stream>>>(
        bfilts, hi0filt, lo0filt, lofilt, AF, L0, L1, L2, L3,
        (const float4*)image, IMG);
    dual_mfma32<<<2048, 256, 0, stream>>>(IMG, out_hi0, L0, AF);
    scale_comb<8, false><<<8 * (512 + 128), 256, 0, stream>>>(
        L0, band_ptr[0][0], band_ptr[0][1], band_ptr[0][2], band_ptr[0][3],
        (void*)L1, AF);
    scale_comb<7, false><<<8 * (128 + 32), 256, 0, stream>>>(
        L1, band_ptr[1][0], band_ptr[1][1], band_ptr[1][2], band_ptr[1][3],
        (void*)L2, AF);
    scale_comb<6, false><<<8 * (32 + 8), 256, 0, stream>>>(
        L2, band_ptr[2][0], band_ptr[2][1], band_ptr[2][2], band_ptr[2][3],
        (void*)L3, AF);
    scale_comb<5, true><<<8 * (8 + 2), 256, 0, stream>>>(
        L3, band_ptr[3][0], band_ptr[3][1], band_ptr[3][2], band_ptr[3][3],
        (void*)out_lofinal, AF);
}

// Round 24
// 114.638 us; speedup vs baseline: 5.0384x; 1.0280x over previous
//
#include <hip/hip_runtime.h>

// Steerable pyramid via MFMA, fp32 I/O, bf16 compute (threshold = 2% of
// per-output absmax; bf16 error ~16384 << 46202, verified r12-r23).
// CX layout for staged images: [n][y][c 16][x] bf16, zero-padded.
// Core (r15): 9-tap convs on mfma_f32_32x32x16_bf16 with fused M
// (bands: 4 bands x 8 px; dual: 2 rows x 2 filters x 8 px; K=16 window),
// down17 on 16x16x32 k-split. D map: col=l&31, row=(reg&3)+8(reg>>2)+4(l>>5).
// r21 diag: band/hi0 stores are 4-scattered-64B-segment instrs -> 2.4TB/s
// (fill kernel: contiguous 1KB/wave -> 6.9TB/s). r22's LDS fix failed from
// serialized RAW on ONE T buffer + dropped nt.
// r24 = r23 + store transpose done right: per-band LDS buffers (no RAW
// serialization: 16 ds_writes back-to-back, one wait, 4 ds_read_b128),
// then 4 contiguous NT global_store_dwordx4 (1KB/wave-instr).

typedef __attribute__((ext_vector_type(8))) short short8v;
typedef __attribute__((ext_vector_type(4))) float f32x4;
typedef __attribute__((ext_vector_type(16))) float f32x16;

static __device__ __forceinline__ unsigned short f2bf(float f) {
    union { float f; unsigned u; } v; v.f = f;
    unsigned u = v.u;
    u += 0x7fffu + ((u >> 16) & 1u);
    return (unsigned short)(u >> 16);
}

static __device__ __forceinline__ unsigned pack2(float a, float b) {
    return (unsigned)f2bf(a) | ((unsigned)f2bf(b) << 16);
}

static __device__ __forceinline__ void nt_storef(float* p, float v) {
    __builtin_nontemporal_store(v, p);
}

static __device__ __forceinline__ void nt_store4(float* p, float4 v) {
    __builtin_nontemporal_store(*(const f32x4*)&v, (f32x4*)p);
}

// AF fragment table rows (entry = short8v per lane, row*64+l):
// [0..8] bands32 dy | [9..18] dual32 i | [19..35] down A1 | [36..52] down A2

// ---------------------------------------------------------------- prep

static __device__ __forceinline__ void do_build_frags(
    const float* bf, const float* fh, const float* fl, const float* lfilt,
    unsigned short* AF, int id)
{
    if (id >= 53 * 64) return;
    int row = id >> 6, l = id & 63;
    short8v a;
    if (row < 9) {
        int dy = row;
        int m = l & 31, f = m >> 3, p = m & 7, kb = (l >> 5) * 8;
        #pragma unroll
        for (int i = 0; i < 8; ++i) {
            int d = kb + i - p;
            a[i] = (short)((d >= 0 && d < 9) ? f2bf(bf[f * 81 + dy * 9 + d]) : 0);
        }
    } else if (row < 19) {
        int is = row - 9;
        int m = l & 31, ry = m >> 4, f = (m >> 3) & 1, p = m & 7, kb = (l >> 5) * 8;
        int dy = is - ry;
        const float* fr = f ? fl : fh;
        #pragma unroll
        for (int i = 0; i < 8; ++i) {
            int dx = kb + i - p;
            bool ok = (dy >= 0 && dy < 9) && (dx >= 0 && dx < 9);
            a[i] = (short)(ok ? f2bf(fr[dy * 9 + dx]) : 0);
        }
    } else if (row < 36) {
        int dy = row - 19;
        int m = l & 15, kb = (l >> 4) * 8;
        #pragma unroll
        for (int i = 0; i < 8; ++i) {
            int d = kb + i - 2 * m;
            a[i] = (short)((d >= 0 && d < 17) ? f2bf(lfilt[dy * 17 + d]) : 0);
        }
    } else {
        int dy = row - 36;
        int m = l & 15, kb = (l >> 4) * 8;
        #pragma unroll
        for (int i = 0; i < 8; ++i) {
            int d = 32 + kb + i - 2 * m;
            a[i] = (short)((d >= 0 && d < 17) ? f2bf(lfilt[dy * 17 + d]) : 0);
        }
    }
    *(short8v*)(AF + (size_t)id * 8) = a;
}

static __device__ __forceinline__ void zero_cx_vec(
    unsigned short* buf, int W, int id)
{
    int Wp = W + 16, Wv = Wp >> 3;
    int rowT = 16 * 16 * Wv;
    int perN = rowT + W * 32;
    int n = id / perN;
    int r = id - n * perN;
    int y, c, xv;
    if (r < rowT) {
        int ry = r / (16 * Wv);
        int rem = r - ry * (16 * Wv);
        c = rem / Wv;
        xv = rem - c * Wv;
        y = (ry < 8) ? ry : ry + W;
    } else {
        int r2 = r - rowT;
        y = 8 + (r2 >> 5);
        int rem = r2 & 31;
        c = rem >> 1;
        xv = (rem & 1) ? (Wv - 1) : 0;
    }
    short8v z = {0, 0, 0, 0, 0, 0, 0, 0};
    *(short8v*)(buf + ((size_t)(n * Wp + y) * 16 + c) * Wp + xv * 8) = z;
}

// prep_all: [0,14) build_frags | [14,1038) zero_pads | [1038,3150) img_to_cx.
__global__ __launch_bounds__(256) void prep_all(
    const float* __restrict__ bf, const float* __restrict__ fh,
    const float* __restrict__ fl, const float* __restrict__ lfilt,
    unsigned short* __restrict__ AF,
    unsigned short* __restrict__ L0, unsigned short* __restrict__ L1,
    unsigned short* __restrict__ L2, unsigned short* __restrict__ L3,
    const float4* __restrict__ src4, unsigned short* __restrict__ IMG)
{
    __shared__ unsigned short lds[16][264];
    int b = blockIdx.x, t = threadIdx.x;
    if (b < 14) {
        do_build_frags(bf, fh, fl, lfilt, AF, b * 256 + t);
    } else if (b < 1038) {
        int zb = b - 14;
        if (zb < 528)      zero_cx_vec(L0, 256, zb * 256 + t);
        else if (zb < 800) zero_cx_vec(L1, 128, (zb - 528) * 256 + t);
        else if (zb < 944) zero_cx_vec(L2, 64,  (zb - 800) * 256 + t);
        else               zero_cx_vec(L3, 32,  (zb - 944) * 256 + t);
    } else {
        int ib = b - 1038;                   // 2112 = 8 * 264
        int n = ib & 7;
        int yp = ib >> 3;
        int y = yp - 4;
        unsigned short* drow = IMG + ((size_t)(n * 264 + yp) * 16) * 264;
        if ((unsigned)y < 256u) {
            for (int task = t; task < 1056; task += 256) {
                int px = task >> 2, cg = task & 3;
                int xs = px - 4;
                bool ok = (unsigned)xs < 256u;
                int xc = min(max(xs, 0), 255);
                float4 v = src4[((size_t)(n * 256 + y) * 256 + xc) * 4 + cg];
                lds[cg * 4 + 0][px] = (unsigned short)(ok ? f2bf(v.x) : 0);
                lds[cg * 4 + 1][px] = (unsigned short)(ok ? f2bf(v.y) : 0);
                lds[cg * 4 + 2][px] = (unsigned short)(ok ? f2bf(v.z) : 0);
                lds[cg * 4 + 3][px] = (unsigned short)(ok ? f2bf(v.w) : 0);
            }
            __syncthreads();
            for (int task = t; task < 528; task += 256) {
                int c = task / 33, xg = task - c * 33;
                short8v v = *(const short8v*)&lds[c][xg * 8];
                *(short8v*)(drow + (size_t)c * 264 + xg * 8) = v;
            }
        } else {
            short8v z = {0, 0, 0, 0, 0, 0, 0, 0};
            for (int task = t; task < 528; task += 256) {
                int c = task / 33, xg = task - c * 33;
                *(short8v*)(drow + (size_t)c * 264 + xg * 8) = z;
            }
        }
    }
}

// ---------------------------------------------------------------- MFMA convs

#define MFMA16 __builtin_amdgcn_mfma_f32_16x16x32_bf16
#define MFMA32 __builtin_amdgcn_mfma_f32_32x32x16_bf16

// hi0 + lo0 from IMG CX (pad 4), 32x32x16, M = 2 rows x 2 filt x 8 px.
// hi0 via per-ry LDS transpose buffers -> contiguous NT dwordx4.
__global__ __launch_bounds__(256) void dual_mfma32(
    const unsigned short* __restrict__ img,
    float* __restrict__ hi0, unsigned short* __restrict__ lo0,
    const unsigned short* __restrict__ AF)
{
    const int RS = 16 * 264;
    __shared__ float tr[4][2][320];
    int n = blockIdx.x & 7;
    int q = blockIdx.x >> 3;
    int xseg = q & 15, yq = q >> 4;
    int t = threadIdx.x, wv = t >> 6, l = t & 63;
    int j = l & 31, pg = j >> 4, c = j & 15, kb = (l >> 5) * 8, hi = l >> 5;
    int x0 = xseg * 16;
    int pbase = (yq * 4 + wv) * 2;
    int wbase = (pg * 8 + 4 * hi) * 20 + c;
    int rdoff = (l >> 2) * 20 + (l & 3) * 4;
    int soff  = (l >> 2) * 16 + (l & 3) * 4;

    short8v A[10];
    #pragma unroll
    for (int i = 0; i < 10; ++i)
        A[i] = *(const short8v*)(AF + ((size_t)((9 + i) * 64 + l)) * 8);

    #pragma unroll
    for (int tp = 0; tp < 2; ++tp) {
        int y = (pbase + tp) * 2;
        const unsigned short* base =
            img + ((size_t)(n * 264 + y) * 16 + c) * 264 + x0 + pg * 8 + kb;
        f32x16 accA = {}, accB = {};
        #pragma unroll
        for (int i = 0; i < 10; i += 2) {
            short8v B0 = *(const short8v*)(base + (size_t)i * RS);
            short8v B1 = *(const short8v*)(base + (size_t)(i + 1) * RS);
            accA = MFMA32(A[i], B0, accA, 0, 0, 0);
            accB = MFMA32(A[i + 1], B1, accB, 0, 0, 0);
        }
        f32x16 acc = accA + accB;
        // write both ry tiles to separate buffers (no RAW serialization)
        #pragma unroll
        for (int ry = 0; ry < 2; ++ry) {
            float* T = tr[wv][ry];
            T[wbase]      = acc[ry * 8 + 0];
            T[wbase + 20] = acc[ry * 8 + 1];
            T[wbase + 40] = acc[ry * 8 + 2];
            T[wbase + 60] = acc[ry * 8 + 3];
        }
        #pragma unroll
        for (int ry = 0; ry < 2; ++ry) {
            size_t so = ((size_t)(n * 256 + y + ry) * 256 + x0) * 16 + soff;
            nt_store4(hi0 + so, *(const float4*)&tr[wv][ry][rdoff]);
            size_t lb = ((size_t)(n * 272 + y + ry + 8) * 16 + c) * 272
                        + (x0 + pg * 8 + 4 * hi + 8);
            int r0 = ry * 8 + 4;
            uint2 pk = make_uint2(pack2(acc[r0], acc[r0 + 1]),
                                  pack2(acc[r0 + 2], acc[r0 + 3]));
            *(uint2*)(lo0 + lb) = pk;
        }
    }
}

// Fused per-scale (clamp-free), 2 tiles/wave fully unrolled.
// Bands: per-band LDS transpose buffers -> 4 contiguous NT dwordx4/tile.
template <int LOGW, bool OUTF32>
__global__ __launch_bounds__(256) void scale_comb(
    const unsigned short* __restrict__ in,
    float* __restrict__ b0, float* __restrict__ b1,
    float* __restrict__ b2, float* __restrict__ b3,
    void* __restrict__ lo_out,
    const unsigned short* __restrict__ AF)
{
    const int W = 1 << LOGW, Wp = W + 16, XS = W / 16, RS = 16 * Wp;
    const int Wo = W >> 1, Wpo = Wo + 16, XS2 = Wo / 16;
    const int bandsPerN = XS * (W / 8);
    __shared__ float tr[4][4][320];
    int n = blockIdx.x & 7;
    int q = blockIdx.x >> 3;
    int t = threadIdx.x, wv = t >> 6, l = t & 63;

    if (q < bandsPerN) {
        int xseg = q & (XS - 1), yq = q >> (LOGW - 4);
        int j = l & 31, pg = j >> 4, c = j & 15, kb = (l >> 5) * 8, hi = l >> 5;
        int x0 = xseg * 16;
        int ybase = (yq * 4 + wv) * 2;
        int wbase = (pg * 8 + 4 * hi) * 20 + c;
        int rdoff = (l >> 2) * 20 + (l & 3) * 4;
        int soff  = (l >> 2) * 16 + (l & 3) * 4;

        short8v A[9];
        #pragma unroll
        for (int dy = 0; dy < 9; ++dy)
            A[dy] = *(const short8v*)(AF + ((size_t)(dy * 64 + l)) * 8);

        #pragma unroll
        for (int ty = 0; ty < 2; ++ty) {
            int y = ybase + ty;
            const unsigned short* base =
                in + ((size_t)(n * Wp + y + 4) * 16 + c) * Wp + x0 + pg * 8 + kb + 4;
            f32x16 accA = {}, accB = {};
            #pragma unroll
            for (int dy = 0; dy < 8; dy += 2) {
                short8v B0 = *(const short8v*)(base + (size_t)dy * RS);
                short8v B1 = *(const short8v*)(base + (size_t)(dy + 1) * RS);
                accA = MFMA32(A[dy], B0, accA, 0, 0, 0);
                accB = MFMA32(A[dy + 1], B1, accB, 0, 0, 0);
            }
            {
                short8v B8 = *(const short8v*)(base + (size_t)8 * RS);
                accA = MFMA32(A[8], B8, accA, 0, 0, 0);
            }
            f32x16 acc = accA + accB;
            // all 16 ds_writes back-to-back (separate per-band buffers)
            #pragma unroll
            for (int f = 0; f < 4; ++f) {
                float* T = tr[wv][f];
                T[wbase]      = acc[f * 4 + 0];
                T[wbase + 20] = acc[f * 4 + 1];
                T[wbase + 40] = acc[f * 4 + 2];
                T[wbase + 60] = acc[f * 4 + 3];
            }
            size_t so = ((size_t)(n * W + y) * W + x0) * 16 + soff;
            nt_store4(b0 + so, *(const float4*)&tr[wv][0][rdoff]);
            nt_store4(b1 + so, *(const float4*)&tr[wv][1][rdoff]);
            nt_store4(b2 + so, *(const float4*)&tr[wv][2][rdoff]);
            nt_store4(b3 + so, *(const float4*)&tr[wv][3][rdoff]);
        }
    } else {
        int q2 = q - bandsPerN;
        int xseg = q2 & (XS2 - 1), yq = q2 >> (LOGW - 5);
        int m = l & 15, g = l >> 4, kb = g * 8;
        int x0 = xseg * 16;
        int ybase = (yq * 4 + wv) * 2;
        int off2 = (g < 2) ? 32 : 0;

        short8v A1[17], A2[17];
        #pragma unroll
        for (int dy = 0; dy < 17; ++dy) {
            A1[dy] = *(const short8v*)(AF + ((size_t)((19 + dy) * 64 + l)) * 8);
            A2[dy] = *(const short8v*)(AF + ((size_t)((36 + dy) * 64 + l)) * 8);
        }

        #pragma unroll
        for (int ty = 0; ty < 2; ++ty) {
            int yo = ybase + ty;
            const unsigned short* base =
                in + ((size_t)(n * Wp + 2 * yo) * 16 + m) * Wp + 2 * x0 + kb;
            f32x4 aA0 = {0, 0, 0, 0}, aA1 = {0, 0, 0, 0};
            f32x4 aB0 = {0, 0, 0, 0}, aB1 = {0, 0, 0, 0};
            #pragma unroll
            for (int dy = 0; dy < 16; dy += 2) {
                short8v B1a = *(const short8v*)(base + (size_t)dy * RS);
                short8v B2a = *(const short8v*)(base + (size_t)dy * RS + off2);
                short8v B1b = *(const short8v*)(base + (size_t)(dy + 1) * RS);
                short8v B2b = *(const short8v*)(base + (size_t)(dy + 1) * RS + off2);
                aA0 = MFMA16(A1[dy], B1a, aA0, 0, 0, 0);
                aB0 = MFMA16(A2[dy], B2a, aB0, 0, 0, 0);
                aA1 = MFMA16(A1[dy + 1], B1b, aA1, 0, 0, 0);
                aB1 = MFMA16(A2[dy + 1], B2b, aB1, 0, 0, 0);
            }
            {
                short8v B1a = *(const short8v*)(base + (size_t)16 * RS);
                short8v B2a = *(const short8v*)(base + (size_t)16 * RS + off2);
                aA0 = MFMA16(A1[16], B1a, aA0, 0, 0, 0);
                aB0 = MFMA16(A2[16], B2a, aB0, 0, 0, 0);
            }
            f32x4 acc = (aA0 + aA1) + (aB0 + aB1);
            if (OUTF32) {
                float* o = (float*)lo_out;
                size_t ob = ((size_t)(n * Wo + yo) * Wo + x0 + g * 4) * 16 + m;
                #pragma unroll
                for (int r = 0; r < 4; ++r) nt_storef(o + ob + (size_t)r * 16, acc[r]);
            } else {
                unsigned short* o = (unsigned short*)lo_out;
                size_t lb = ((size_t)(n * Wpo + yo + 8) * 16 + m) * Wpo + (x0 + 8 + g * 4);
                uint2 pk = make_uint2(pack2(acc[0], acc[1]),
                                      pack2(acc[2], acc[3]));
                *(uint2*)(o + lb) = pk;
            }
        }
    }
}

// ---------------------------------------------------------------- launch

extern "C" void kernel_launch(void* const* d_in, const int* in_sizes, int n_in,
                              void* d_out, int out_size, void* d_ws, size_t ws_size,
                              hipStream_t stream) {
    const float* image   = (const float*)d_in[0];
    const float* lo0filt = (const float*)d_in[1];
    const float* hi0filt = (const float*)d_in[2];
    const float* lofilt  = (const float*)d_in[3];
    const float* bfilts  = (const float*)d_in[4];
    float* out = (float*)d_out;

    const int N = 8, C = 16;
    size_t sz[5];
    const int Ws[5] = {256, 128, 64, 32, 16};
    for (int s = 0; s < 5; ++s) sz[s] = (size_t)N * Ws[s] * Ws[s] * C;

    // Workspace (ushort units): AF table, IMG CX (pad4), L0..L3 CX (pad8).
    unsigned short* wsu = (unsigned short*)d_ws;
    unsigned short* AF  = wsu;                       // 53*64*8 -> pad to 32768
    unsigned short* IMG = AF + 32768;
    unsigned short* L0 = IMG + (size_t)N * 264 * 16 * 264;
    unsigned short* L1 = L0 + (size_t)N * 272 * 16 * 272;
    unsigned short* L2 = L1 + (size_t)N * 144 * 16 * 144;
    unsigned short* L3 = L2 + (size_t)N * 80 * 16 * 80;

    // Output layout (reversed pyramid, flat):
    // [ lo_final | s=3 b=3..0 | s=2 b=3..0 | s=1 b=3..0 | s=0 b=3..0 | hi0 ]
    float* out_lofinal = out;
    size_t o = sz[4];
    float* band_ptr[4][4];
    for (int s = 3; s >= 0; --s)
        for (int b = 3; b >= 0; --b) { band_ptr[s][b] = out + o; o += sz[s]; }
    float* out_hi0 = out + o;

    prep_all<<<3150, 256, 0, stream>>>(
        bfilts, hi0filt, lo0filt, lofilt, AF, L0, L1, L2, L3,
        (const float4*)image, IMG);
    dual_mfma32<<<2048, 256, 0, stream>>>(IMG, out_hi0, L0, AF);
    scale_comb<8, false><<<8 * (512 + 128), 256, 0, stream>>>(
        L0, band_ptr[0][0], band_ptr[0][1], band_ptr[0][2], band_ptr[0][3],
        (void*)L1, AF);
    scale_comb<7, false><<<8 * (128 + 32), 256, 0, stream>>>(
        L1, band_ptr[1][0], band_ptr[1][1], band_ptr[1][2], band_ptr[1][3],
        (void*)L2, AF);
    scale_comb<6, false><<<8 * (32 + 8), 256, 0, stream>>>(
        L2, band_ptr[2][0], band_ptr[2][1], band_ptr[2][2], band_ptr[2][3],
        (void*)L3, AF);
    scale_comb<5, true><<<8 * (8 + 2), 256, 0, stream>>>(
        L3, band_ptr[3][0], band_ptr[3][1], band_ptr[3][2], band_ptr[3][3],
        (void*)out_lofinal, AF);
}

// Round 25
// 114.360 us; speedup vs baseline: 5.0507x; 1.0024x over previous
//
#include <hip/hip_runtime.h>

// Steerable pyramid via MFMA, fp32 I/O, bf16 compute (threshold = 2% of
// per-output absmax; bf16 error ~16384 << 46202, verified r12-r24).
// CX layout for staged images: [n][y][c 16][x] bf16, zero-padded.
// Core (r15): 9-tap convs on mfma_f32_32x32x16_bf16 with fused M
// (bands: 4 bands x 8 px; dual: 2 rows x 2 filters x 8 px; K=16 window),
// down17 on 16x16x32 k-split. D map: col=l&31, row=(reg&3)+8(reg>>2)+4(l>>5).
// r24: per-band LDS store transpose -> contiguous NT dwordx4 (kept).
// r25: EXPLICIT B-ROW SHARING across the 2-tile unroll: bands load the
// 10-row union once (tile0 uses B[dy], tile1 B[dy+1]) -> 18->10 loads;
// dual loads 12-row union (tile0 B[0..9], tile1 B[2..11]) -> 20->12.
// All loads issue up-front; MFMA stream covers their latency.

typedef __attribute__((ext_vector_type(8))) short short8v;
typedef __attribute__((ext_vector_type(4))) float f32x4;
typedef __attribute__((ext_vector_type(16))) float f32x16;

static __device__ __forceinline__ unsigned short f2bf(float f) {
    union { float f; unsigned u; } v; v.f = f;
    unsigned u = v.u;
    u += 0x7fffu + ((u >> 16) & 1u);
    return (unsigned short)(u >> 16);
}

static __device__ __forceinline__ unsigned pack2(float a, float b) {
    return (unsigned)f2bf(a) | ((unsigned)f2bf(b) << 16);
}

static __device__ __forceinline__ void nt_storef(float* p, float v) {
    __builtin_nontemporal_store(v, p);
}

static __device__ __forceinline__ void nt_store4(float* p, float4 v) {
    __builtin_nontemporal_store(*(const f32x4*)&v, (f32x4*)p);
}

// AF fragment table rows (entry = short8v per lane, row*64+l):
// [0..8] bands32 dy | [9..18] dual32 i | [19..35] down A1 | [36..52] down A2

// ---------------------------------------------------------------- prep

static __device__ __forceinline__ void do_build_frags(
    const float* bf, const float* fh, const float* fl, const float* lfilt,
    unsigned short* AF, int id)
{
    if (id >= 53 * 64) return;
    int row = id >> 6, l = id & 63;
    short8v a;
    if (row < 9) {
        int dy = row;
        int m = l & 31, f = m >> 3, p = m & 7, kb = (l >> 5) * 8;
        #pragma unroll
        for (int i = 0; i < 8; ++i) {
            int d = kb + i - p;
            a[i] = (short)((d >= 0 && d < 9) ? f2bf(bf[f * 81 + dy * 9 + d]) : 0);
        }
    } else if (row < 19) {
        int is = row - 9;
        int m = l & 31, ry = m >> 4, f = (m >> 3) & 1, p = m & 7, kb = (l >> 5) * 8;
        int dy = is - ry;
        const float* fr = f ? fl : fh;
        #pragma unroll
        for (int i = 0; i < 8; ++i) {
            int dx = kb + i - p;
            bool ok = (dy >= 0 && dy < 9) && (dx >= 0 && dx < 9);
            a[i] = (short)(ok ? f2bf(fr[dy * 9 + dx]) : 0);
        }
    } else if (row < 36) {
        int dy = row - 19;
        int m = l & 15, kb = (l >> 4) * 8;
        #pragma unroll
        for (int i = 0; i < 8; ++i) {
            int d = kb + i - 2 * m;
            a[i] = (short)((d >= 0 && d < 17) ? f2bf(lfilt[dy * 17 + d]) : 0);
        }
    } else {
        int dy = row - 36;
        int m = l & 15, kb = (l >> 4) * 8;
        #pragma unroll
        for (int i = 0; i < 8; ++i) {
            int d = 32 + kb + i - 2 * m;
            a[i] = (short)((d >= 0 && d < 17) ? f2bf(lfilt[dy * 17 + d]) : 0);
        }
    }
    *(short8v*)(AF + (size_t)id * 8) = a;
}

static __device__ __forceinline__ void zero_cx_vec(
    unsigned short* buf, int W, int id)
{
    int Wp = W + 16, Wv = Wp >> 3;
    int rowT = 16 * 16 * Wv;
    int perN = rowT + W * 32;
    int n = id / perN;
    int r = id - n * perN;
    int y, c, xv;
    if (r < rowT) {
        int ry = r / (16 * Wv);
        int rem = r - ry * (16 * Wv);
        c = rem / Wv;
        xv = rem - c * Wv;
        y = (ry < 8) ? ry : ry + W;
    } else {
        int r2 = r - rowT;
        y = 8 + (r2 >> 5);
        int rem = r2 & 31;
        c = rem >> 1;
        xv = (rem & 1) ? (Wv - 1) : 0;
    }
    short8v z = {0, 0, 0, 0, 0, 0, 0, 0};
    *(short8v*)(buf + ((size_t)(n * Wp + y) * 16 + c) * Wp + xv * 8) = z;
}

// prep_all: [0,14) build_frags | [14,1038) zero_pads | [1038,3150) img_to_cx.
__global__ __launch_bounds__(256) void prep_all(
    const float* __restrict__ bf, const float* __restrict__ fh,
    const float* __restrict__ fl, const float* __restrict__ lfilt,
    unsigned short* __restrict__ AF,
    unsigned short* __restrict__ L0, unsigned short* __restrict__ L1,
    unsigned short* __restrict__ L2, unsigned short* __restrict__ L3,
    const float4* __restrict__ src4, unsigned short* __restrict__ IMG)
{
    __shared__ unsigned short lds[16][264];
    int b = blockIdx.x, t = threadIdx.x;
    if (b < 14) {
        do_build_frags(bf, fh, fl, lfilt, AF, b * 256 + t);
    } else if (b < 1038) {
        int zb = b - 14;
        if (zb < 528)      zero_cx_vec(L0, 256, zb * 256 + t);
        else if (zb < 800) zero_cx_vec(L1, 128, (zb - 528) * 256 + t);
        else if (zb < 944) zero_cx_vec(L2, 64,  (zb - 800) * 256 + t);
        else               zero_cx_vec(L3, 32,  (zb - 944) * 256 + t);
    } else {
        int ib = b - 1038;                   // 2112 = 8 * 264
        int n = ib & 7;
        int yp = ib >> 3;
        int y = yp - 4;
        unsigned short* drow = IMG + ((size_t)(n * 264 + yp) * 16) * 264;
        if ((unsigned)y < 256u) {
            for (int task = t; task < 1056; task += 256) {
                int px = task >> 2, cg = task & 3;
                int xs = px - 4;
                bool ok = (unsigned)xs < 256u;
                int xc = min(max(xs, 0), 255);
                float4 v = src4[((size_t)(n * 256 + y) * 256 + xc) * 4 + cg];
                lds[cg * 4 + 0][px] = (unsigned short)(ok ? f2bf(v.x) : 0);
                lds[cg * 4 + 1][px] = (unsigned short)(ok ? f2bf(v.y) : 0);
                lds[cg * 4 + 2][px] = (unsigned short)(ok ? f2bf(v.z) : 0);
                lds[cg * 4 + 3][px] = (unsigned short)(ok ? f2bf(v.w) : 0);
            }
            __syncthreads();
            for (int task = t; task < 528; task += 256) {
                int c = task / 33, xg = task - c * 33;
                short8v v = *(const short8v*)&lds[c][xg * 8];
                *(short8v*)(drow + (size_t)c * 264 + xg * 8) = v;
            }
        } else {
            short8v z = {0, 0, 0, 0, 0, 0, 0, 0};
            for (int task = t; task < 528; task += 256) {
                int c = task / 33, xg = task - c * 33;
                *(short8v*)(drow + (size_t)c * 264 + xg * 8) = z;
            }
        }
    }
}

// ---------------------------------------------------------------- MFMA convs

#define MFMA16 __builtin_amdgcn_mfma_f32_16x16x32_bf16
#define MFMA32 __builtin_amdgcn_mfma_f32_32x32x16_bf16

// hi0 + lo0 from IMG CX (pad 4), 32x32x16, M = 2 rows x 2 filt x 8 px.
// 12-row B union loaded once; tile0 uses B[0..9], tile1 B[2..11].
__global__ __launch_bounds__(256) void dual_mfma32(
    const unsigned short* __restrict__ img,
    float* __restrict__ hi0, unsigned short* __restrict__ lo0,
    const unsigned short* __restrict__ AF)
{
    const int RS = 16 * 264;
    __shared__ float tr[4][2][320];
    int n = blockIdx.x & 7;
    int q = blockIdx.x >> 3;
    int xseg = q & 15, yq = q >> 4;
    int t = threadIdx.x, wv = t >> 6, l = t & 63;
    int j = l & 31, pg = j >> 4, c = j & 15, kb = (l >> 5) * 8, hi = l >> 5;
    int x0 = xseg * 16;
    int pbase = (yq * 4 + wv) * 2;
    int y0 = pbase * 2;
    int wbase = (pg * 8 + 4 * hi) * 20 + c;
    int rdoff = (l >> 2) * 20 + (l & 3) * 4;
    int soff  = (l >> 2) * 16 + (l & 3) * 4;

    short8v A[10];
    #pragma unroll
    for (int i = 0; i < 10; ++i)
        A[i] = *(const short8v*)(AF + ((size_t)((9 + i) * 64 + l)) * 8);

    // 12-row union of both tiles' B operands
    const unsigned short* ub =
        img + ((size_t)(n * 264 + y0) * 16 + c) * 264 + x0 + pg * 8 + kb;
    short8v B[12];
    #pragma unroll
    for (int r = 0; r < 12; ++r)
        B[r] = *(const short8v*)(ub + (size_t)r * RS);

    #pragma unroll
    for (int tp = 0; tp < 2; ++tp) {
        int y = y0 + tp * 2;
        f32x16 accA = {}, accB = {};
        #pragma unroll
        for (int i = 0; i < 10; i += 2) {
            accA = MFMA32(A[i], B[tp * 2 + i], accA, 0, 0, 0);
            accB = MFMA32(A[i + 1], B[tp * 2 + i + 1], accB, 0, 0, 0);
        }
        f32x16 acc = accA + accB;
        #pragma unroll
        for (int ry = 0; ry < 2; ++ry) {
            float* T = tr[wv][ry];
            T[wbase]      = acc[ry * 8 + 0];
            T[wbase + 20] = acc[ry * 8 + 1];
            T[wbase + 40] = acc[ry * 8 + 2];
            T[wbase + 60] = acc[ry * 8 + 3];
        }
        #pragma unroll
        for (int ry = 0; ry < 2; ++ry) {
            size_t so = ((size_t)(n * 256 + y + ry) * 256 + x0) * 16 + soff;
            nt_store4(hi0 + so, *(const float4*)&tr[wv][ry][rdoff]);
            size_t lb = ((size_t)(n * 272 + y + ry + 8) * 16 + c) * 272
                        + (x0 + pg * 8 + 4 * hi + 8);
            int r0 = ry * 8 + 4;
            uint2 pk = make_uint2(pack2(acc[r0], acc[r0 + 1]),
                                  pack2(acc[r0 + 2], acc[r0 + 3]));
            *(uint2*)(lo0 + lb) = pk;
        }
    }
}

// Fused per-scale (clamp-free), 2 tiles/wave fully unrolled.
// Bands: 10-row B union loaded once (tile0 B[dy], tile1 B[dy+1]);
// per-band LDS transpose -> contiguous NT dwordx4.
template <int LOGW, bool OUTF32>
__global__ __launch_bounds__(256) void scale_comb(
    const unsigned short* __restrict__ in,
    float* __restrict__ b0, float* __restrict__ b1,
    float* __restrict__ b2, float* __restrict__ b3,
    void* __restrict__ lo_out,
    const unsigned short* __restrict__ AF)
{
    const int W = 1 << LOGW, Wp = W + 16, XS = W / 16, RS = 16 * Wp;
    const int Wo = W >> 1, Wpo = Wo + 16, XS2 = Wo / 16;
    const int bandsPerN = XS * (W / 8);
    __shared__ float tr[4][4][320];
    int n = blockIdx.x & 7;
    int q = blockIdx.x >> 3;
    int t = threadIdx.x, wv = t >> 6, l = t & 63;

    if (q < bandsPerN) {
        int xseg = q & (XS - 1), yq = q >> (LOGW - 4);
        int j = l & 31, pg = j >> 4, c = j & 15, kb = (l >> 5) * 8, hi = l >> 5;
        int x0 = xseg * 16;
        int ybase = (yq * 4 + wv) * 2;
        int wbase = (pg * 8 + 4 * hi) * 20 + c;
        int rdoff = (l >> 2) * 20 + (l & 3) * 4;
        int soff  = (l >> 2) * 16 + (l & 3) * 4;

        short8v A[9];
        #pragma unroll
        for (int dy = 0; dy < 9; ++dy)
            A[dy] = *(const short8v*)(AF + ((size_t)(dy * 64 + l)) * 8);

        // 10-row union of both tiles' B operands
        const unsigned short* ub =
            in + ((size_t)(n * Wp + ybase + 4) * 16 + c) * Wp + x0 + pg * 8 + kb + 4;
        short8v B[10];
        #pragma unroll
        for (int r = 0; r < 10; ++r)
            B[r] = *(const short8v*)(ub + (size_t)r * RS);

        #pragma unroll
        for (int ty = 0; ty < 2; ++ty) {
            int y = ybase + ty;
            f32x16 accA = {}, accB = {};
            #pragma unroll
            for (int dy = 0; dy < 8; dy += 2) {
                accA = MFMA32(A[dy], B[dy + ty], accA, 0, 0, 0);
                accB = MFMA32(A[dy + 1], B[dy + 1 + ty], accB, 0, 0, 0);
            }
            accA = MFMA32(A[8], B[8 + ty], accA, 0, 0, 0);
            f32x16 acc = accA + accB;
            #pragma unroll
            for (int f = 0; f < 4; ++f) {
                float* T = tr[wv][f];
                T[wbase]      = acc[f * 4 + 0];
                T[wbase + 20] = acc[f * 4 + 1];
                T[wbase + 40] = acc[f * 4 + 2];
                T[wbase + 60] = acc[f * 4 + 3];
            }
            size_t so = ((size_t)(n * W + y) * W + x0) * 16 + soff;
            nt_store4(b0 + so, *(const float4*)&tr[wv][0][rdoff]);
            nt_store4(b1 + so, *(const float4*)&tr[wv][1][rdoff]);
            nt_store4(b2 + so, *(const float4*)&tr[wv][2][rdoff]);
            nt_store4(b3 + so, *(const float4*)&tr[wv][3][rdoff]);
        }
    } else {
        int q2 = q - bandsPerN;
        int xseg = q2 & (XS2 - 1), yq = q2 >> (LOGW - 5);
        int m = l & 15, g = l >> 4, kb = g * 8;
        int x0 = xseg * 16;
        int ybase = (yq * 4 + wv) * 2;
        int off2 = (g < 2) ? 32 : 0;

        short8v A1[17], A2[17];
        #pragma unroll
        for (int dy = 0; dy < 17; ++dy) {
            A1[dy] = *(const short8v*)(AF + ((size_t)((19 + dy) * 64 + l)) * 8);
            A2[dy] = *(const short8v*)(AF + ((size_t)((36 + dy) * 64 + l)) * 8);
        }

        #pragma unroll
        for (int ty = 0; ty < 2; ++ty) {
            int yo = ybase + ty;
            const unsigned short* base =
                in + ((size_t)(n * Wp + 2 * yo) * 16 + m) * Wp + 2 * x0 + kb;
            f32x4 aA0 = {0, 0, 0, 0}, aA1 = {0, 0, 0, 0};
            f32x4 aB0 = {0, 0, 0, 0}, aB1 = {0, 0, 0, 0};
            #pragma unroll
            for (int dy = 0; dy < 16; dy += 2) {
                short8v B1a = *(const short8v*)(base + (size_t)dy * RS);
                short8v B2a = *(const short8v*)(base + (size_t)dy * RS + off2);
                short8v B1b = *(const short8v*)(base + (size_t)(dy + 1) * RS);
                short8v B2b = *(const short8v*)(base + (size_t)(dy + 1) * RS + off2);
                aA0 = MFMA16(A1[dy], B1a, aA0, 0, 0, 0);
                aB0 = MFMA16(A2[dy], B2a, aB0, 0, 0, 0);
                aA1 = MFMA16(A1[dy + 1], B1b, aA1, 0, 0, 0);
                aB1 = MFMA16(A2[dy + 1], B2b, aB1, 0, 0, 0);
            }
            {
                short8v B1a = *(const short8v*)(base + (size_t)16 * RS);
                short8v B2a = *(const short8v*)(base + (size_t)16 * RS + off2);
                aA0 = MFMA16(A1[16], B1a, aA0, 0, 0, 0);
                aB0 = MFMA16(A2[16], B2a, aB0, 0, 0, 0);
            }
            f32x4 acc = (aA0 + aA1) + (aB0 + aB1);
            if (OUTF32) {
                float* o = (float*)lo_out;
                size_t ob = ((size_t)(n * Wo + yo) * Wo + x0 + g * 4) * 16 + m;
                #pragma unroll
                for (int r = 0; r < 4; ++r) nt_storef(o + ob + (size_t)r * 16, acc[r]);
            } else {
                unsigned short* o = (unsigned short*)lo_out;
                size_t lb = ((size_t)(n * Wpo + yo + 8) * 16 + m) * Wpo + (x0 + 8 + g * 4);
                uint2 pk = make_uint2(pack2(acc[0], acc[1]),
                                      pack2(acc[2], acc[3]));
                *(uint2*)(o + lb) = pk;
            }
        }
    }
}

// ---------------------------------------------------------------- launch

extern "C" void kernel_launch(void* const* d_in, const int* in_sizes, int n_in,
                              void* d_out, int out_size, void* d_ws, size_t ws_size,
                              hipStream_t stream) {
    const float* image   = (const float*)d_in[0];
    const float* lo0filt = (const float*)d_in[1];
    const float* hi0filt = (const float*)d_in[2];
    const float* lofilt  = (const float*)d_in[3];
    const float* bfilts  = (const float*)d_in[4];
    float* out = (float*)d_out;

    const int N = 8, C = 16;
    size_t sz[5];
    const int Ws[5] = {256, 128, 64, 32, 16};
    for (int s = 0; s < 5; ++s) sz[s] = (size_t)N * Ws[s] * Ws[s] * C;

    // Workspace (ushort units): AF table, IMG CX (pad4), L0..L3 CX (pad8).
    unsigned short* wsu = (unsigned short*)d_ws;
    unsigned short* AF  = wsu;                       // 53*64*8 -> pad to 32768
    unsigned short* IMG = AF + 32768;
    unsigned short* L0 = IMG + (size_t)N * 264 * 16 * 264;
    unsigned short* L1 = L0 + (size_t)N * 272 * 16 * 272;
    unsigned short* L2 = L1 + (size_t)N * 144 * 16 * 144;
    unsigned short* L3 = L2 + (size_t)N * 80 * 16 * 80;

    // Output layout (reversed pyramid, flat):
    // [ lo_final | s=3 b=3..0 | s=2 b=3..0 | s=1 b=3..0 | s=0 b=3..0 | hi0 ]
    float* out_lofinal = out;
    size_t o = sz[4];
    float* band_ptr[4][4];
    for (int s = 3; s >= 0; --s)
        for (int b = 3; b >= 0; --b) { band_ptr[s][b] = out + o; o += sz[s]; }
    float* out_hi0 = out + o;

    prep_all<<<3150, 256, 0, stream>>>(
        bfilts, hi0filt, lo0filt, lofilt, AF, L0, L1, L2, L3,
        (const float4*)image, IMG);
    dual_mfma32<<<2048, 256, 0, stream>>>(IMG, out_hi0, L0, AF);
    scale_comb<8, false><<<8 * (512 + 128), 256, 0, stream>>>(
        L0, band_ptr[0][0], band_ptr[0][1], band_ptr[0][2], band_ptr[0][3],
        (void*)L1, AF);
    scale_comb<7, false><<<8 * (128 + 32), 256, 0, stream>>>(
        L1, band_ptr[1][0], band_ptr[1][1], band_ptr[1][2], band_ptr[1][3],
        (void*)L2, AF);
    scale_comb<6, false><<<8 * (32 + 8), 256, 0, stream>>>(
        L2, band_ptr[2][0], band_ptr[2][1], band_ptr[2][2], band_ptr[2][3],
        (void*)L3, AF);
    scale_comb<5, true><<<8 * (8 + 2), 256, 0, stream>>>(
        L3, band_ptr[3][0], band_ptr[3][1], band_ptr[3][2], band_ptr[3][3],
        (void*)out_lofinal, AF);
}